// Round 12
// baseline (214.702 us; speedup 1.0000x reference)
//
#include <hip/hip_runtime.h>

// GraphAttention N=4096 F=1024 H=8 U=128.
// R12: gemm split-K x2 into partial buffers (512 blocks -> 2 blocks/CU,
// 4 waves/SIMD; was 1 block/CU latency-bound at MfmaUtil 22%). New reduce_add
// kernel sums partials (featH|s|t contiguous). No atomics, no zero-init.
// prep/transposeW/aggregate unchanged from R11 (verified).

constexpr int NN = 4096;
constexpr int FF = 1024;
constexpr int HH = 8;
constexpr int UU = 128;
constexpr int CC = HH * UU;
constexpr int MAXDEG = 128;
constexpr float ALPHA = 0.2f;
constexpr size_t FEAT_ELEMS = (size_t)NN * CC;        // 4,194,304
constexpr size_t ST_ELEMS = (size_t)HH * NN;          // 32,768
constexpr size_t OUTBLK = FEAT_ELEMS + 2 * ST_ELEMS;  // 4,259,840 = 1040*4096

typedef __attribute__((ext_vector_type(8))) short short8;   // 8 bf16 (4 VGPRs)
typedef __attribute__((ext_vector_type(4))) float f32x4;

__device__ inline unsigned short f2bf(float x) {  // RNE float->bf16
  unsigned u = __float_as_uint(x);
  return (unsigned short)((u + 0x7fffu + ((u >> 16) & 1u)) >> 16);
}
__device__ inline float bf2f(unsigned short h) { return __uint_as_float(((unsigned)h) << 16); }

// --------------------------- K0b: W[h][f][u] -> WT[{hi,lo}][h][u][f] (bf16)
__global__ __launch_bounds__(256) void transposeW(const float* __restrict__ W,
                                                  unsigned short* __restrict__ WT) {
  const int h = blockIdx.x >> 3, ft = blockIdx.x & 7;
  const int f0 = ft * 128;
  __shared__ unsigned short hiT[128][136];  // [u][f_local], +8 pad
  __shared__ unsigned short loT[128][136];
  const int tid = threadIdx.x;
#pragma unroll
  for (int it = 0; it < 16; ++it) {
    int idx = it * 256 + tid;  // 128 f x 32 u4
    int r = idx >> 5;
    int u4 = idx & 31;
    float4 v = *(const float4*)(W + (size_t)h * FF * UU + (size_t)(f0 + r) * UU + u4 * 4);
    float xs[4] = {v.x, v.y, v.z, v.w};
#pragma unroll
    for (int e = 0; e < 4; ++e) {
      unsigned short hb = f2bf(xs[e]);
      hiT[u4 * 4 + e][r] = hb;
      loT[u4 * 4 + e][r] = f2bf(xs[e] - bf2f(hb));
    }
  }
  __syncthreads();
#pragma unroll
  for (int it = 0; it < 8; ++it) {
    int idx = it * 256 + tid;  // 128 u x 16 f8
    int u = idx >> 4, f8 = idx & 15;
    short8 vh = *(const short8*)&hiT[u][f8 * 8];
    short8 vl = *(const short8*)&loT[u][f8 * 8];
    size_t o = (size_t)h * UU * FF + (size_t)u * FF + f0 + f8 * 8;
    *(short8*)(WT + o) = vh;
    *(short8*)(WT + (size_t)HH * UU * FF + o) = vl;
  }
}

// ---------------- K1: fused prep — convert_X (blocks 0..2047) ∥ build_csr
__global__ __launch_bounds__(256) void prep(const float* __restrict__ X,
                                            unsigned short* __restrict__ Xhi,
                                            unsigned short* __restrict__ Xlo,
                                            const float* __restrict__ A,
                                            int* __restrict__ deg,
                                            int* __restrict__ idx) {
  const int tid = threadIdx.x;
  if (blockIdx.x < 2048) {  // ---- convert_X part
    size_t base = ((size_t)blockIdx.x * 256 + tid) * 8;
    float4 v0 = *(const float4*)(X + base);
    float4 v1 = *(const float4*)(X + base + 4);
    float xs[8] = {v0.x, v0.y, v0.z, v0.w, v1.x, v1.y, v1.z, v1.w};
    short8 vh, vl;
#pragma unroll
    for (int e = 0; e < 8; ++e) {
      unsigned short hb = f2bf(xs[e]);
      vh[e] = (short)hb;
      vl[e] = (short)f2bf(xs[e] - bf2f(hb));
    }
    *(short8*)(Xhi + base) = vh;
    *(short8*)(Xlo + base) = vl;
    return;
  }
  // ---- build_csr part (ballot compaction)
  const int i = blockIdx.x - 2048;
  const int lane = tid & 63;
  __shared__ int cnt;
  if (tid == 0) cnt = 0;
  __syncthreads();
  const float4* row = reinterpret_cast<const float4*>(A + (size_t)i * NN);
  for (int c = tid; c < NN / 4; c += 256) {
    float4 v = row[c];
    unsigned long long m0 = __ballot(v.x > 0.5f);
    unsigned long long m1 = __ballot(v.y > 0.5f);
    unsigned long long m2 = __ballot(v.z > 0.5f);
    unsigned long long m3 = __ballot(v.w > 0.5f);
    int wtot = __popcll(m0) + __popcll(m1) + __popcll(m2) + __popcll(m3);
    if (wtot) {
      int base = 0;
      if (lane == 0) base = atomicAdd(&cnt, wtot);
      base = __shfl(base, 0);
      unsigned long long lt = (1ull << lane) - 1;
      int c0 = __popcll(m0), c1 = __popcll(m1), c2 = __popcll(m2);
      int o;
      o = base + __popcll(m0 & lt);
      if (v.x > 0.5f && o < MAXDEG) idx[i * MAXDEG + o] = c * 4 + 0;
      o = base + c0 + __popcll(m1 & lt);
      if (v.y > 0.5f && o < MAXDEG) idx[i * MAXDEG + o] = c * 4 + 1;
      o = base + c0 + c1 + __popcll(m2 & lt);
      if (v.z > 0.5f && o < MAXDEG) idx[i * MAXDEG + o] = c * 4 + 2;
      o = base + c0 + c1 + c2 + __popcll(m3 & lt);
      if (v.w > 0.5f && o < MAXDEG) idx[i * MAXDEG + o] = c * 4 + 3;
    }
  }
  __syncthreads();
  if (tid == 0) deg[i] = cnt > MAXDEG ? MAXDEG : cnt;
}

// --------------------- K2: feat = X @ W via split-bf16 MFMA (K=3*1024)
// Split-K x2: z = bid>>8 picks tiles [z*24, z*24+24); halves write disjoint
// partial buffers pA/pB (layout featH|s|t). XCD(bid)=rt%8 for both halves.
__global__ __launch_bounds__(512) void gemm_mfma(const unsigned short* __restrict__ Xhi,
                                                 const unsigned short* __restrict__ Xlo,
                                                 const unsigned short* __restrict__ WT,
                                                 const float* __restrict__ a_self,
                                                 const float* __restrict__ a_neigh,
                                                 float* __restrict__ pA,
                                                 float* __restrict__ pB) {
  __shared__ char lds[2][32768];  // [buf][ A 16K | B 16K ]
  const int tid = threadIdx.x;
  const int w = tid >> 6, l = tid & 63;
  const int bid = blockIdx.x;
  const int z = bid >> 8;
  const int bid8 = bid & 255;
  const int h = bid8 >> 5;             // head = high bits
  const int row0 = (bid8 & 31) * 128;  // rowtile = low bits -> XCD=rt%8
  const int wr = w >> 2, wc = w & 3;
  const int t0 = z * 24;

  float* pf = z ? pB : pA;             // partial featH
  float* ps = pf + FEAT_ELEMS;         // partial s
  float* pt = ps + ST_ELEMS;           // partial t

  const int lr = l >> 3;               // staged LDS row within 8-row group
  const int sk = ((l & 7) ^ lr) * 8;   // inverse-swizzled source k-elem
  const unsigned short* WTh = WT + (size_t)h * UU * FF;

  f32x4 acc[4][2] = {};

  auto stage = [&](int t, int buf) {
    int s = t >> 4, kt = t & 15;
    const unsigned short* As = ((s == 1) ? Xlo : Xhi) +
        (size_t)(row0 + w * 16 + lr) * FF + kt * 64 + sk;
    const unsigned short* Bs = WTh + ((s == 2) ? (size_t)HH * UU * FF : (size_t)0) +
        (size_t)(w * 16 + lr) * FF + kt * 64 + sk;
    char* la = &lds[buf][w * 2048];
    char* lb = &lds[buf][16384 + w * 2048];
#pragma unroll
    for (int dr = 0; dr < 2; ++dr) {
      __builtin_amdgcn_global_load_lds(
          (const __attribute__((address_space(1))) unsigned int*)(As + (size_t)dr * 8 * FF),
          (__attribute__((address_space(3))) unsigned int*)(la + dr * 1024), 16, 0, 0);
      __builtin_amdgcn_global_load_lds(
          (const __attribute__((address_space(1))) unsigned int*)(Bs + (size_t)dr * 8 * FF),
          (__attribute__((address_space(3))) unsigned int*)(lb + dr * 1024), 16, 0, 0);
    }
  };

  const int arow = wr * 64 + (l & 15);
  const int bcol = wc * 32 + (l & 15);
  const int kswz = (l & 7) << 4;
  const int kb = (l >> 4) * 16;

  auto compute = [&](int buf) {
#pragma unroll
    for (int ks = 0; ks < 2; ++ks) {
      const int ko = ks * 64 + kb;
      short8 a[4], b[2];
#pragma unroll
      for (int mi = 0; mi < 4; ++mi)
        a[mi] = *(const short8*)(&lds[buf][(arow + mi * 16) * 128 + (ko ^ kswz)]);
#pragma unroll
      for (int ni = 0; ni < 2; ++ni)
        b[ni] = *(const short8*)(&lds[buf][16384 + (bcol + ni * 16) * 128 + (ko ^ kswz)]);
#pragma unroll
      for (int mi = 0; mi < 4; ++mi)
#pragma unroll
        for (int ni = 0; ni < 2; ++ni)
          acc[mi][ni] = __builtin_amdgcn_mfma_f32_16x16x32_bf16(a[mi], b[ni],
                                                                acc[mi][ni], 0, 0, 0);
    }
  };

  stage(t0, 0);
  __syncthreads();
  for (int tt = 0; tt < 24; ++tt) {
    if (tt + 1 < 24) stage(t0 + tt + 1, (tt + 1) & 1);
    compute(tt & 1);
    __syncthreads();
  }

  // ---- partial C write (head-major): pf[h][row][u]
  float* fh = pf + (size_t)h * NN * UU;
  const int cu = wc * 32 + (l & 15);
  const int crow0 = row0 + wr * 64 + (l >> 4) * 4;
#pragma unroll
  for (int mi = 0; mi < 4; ++mi)
#pragma unroll
    for (int ni = 0; ni < 2; ++ni)
#pragma unroll
      for (int r = 0; r < 4; ++r)
        fh[(size_t)(crow0 + mi * 16 + r) * UU + cu + ni * 16] = acc[mi][ni][r];

  // ---- fused partial s/t
  const float as0 = a_self[h * UU + cu], as1 = a_self[h * UU + cu + 16];
  const float an0 = a_neigh[h * UU + cu], an1 = a_neigh[h * UU + cu + 16];
  float psr[16], ptr_[16];
#pragma unroll
  for (int mi = 0; mi < 4; ++mi)
#pragma unroll
    for (int r = 0; r < 4; ++r) {
      psr[mi * 4 + r] = acc[mi][0][r] * as0 + acc[mi][1][r] * as1;
      ptr_[mi * 4 + r] = acc[mi][0][r] * an0 + acc[mi][1][r] * an1;
    }
#pragma unroll
  for (int mask = 1; mask <= 8; mask <<= 1)
#pragma unroll
    for (int q = 0; q < 16; ++q) {
      psr[q] += __shfl_xor(psr[q], mask);
      ptr_[q] += __shfl_xor(ptr_[q], mask);
    }
  float(*sred)[4] = (float(*)[4]) & lds[0][0];      // [128][4]
  float(*tred)[4] = (float(*)[4]) & lds[0][2048];   // [128][4]
  if ((l & 15) == 0) {
#pragma unroll
    for (int mi = 0; mi < 4; ++mi)
#pragma unroll
      for (int r = 0; r < 4; ++r) {
        int rl = wr * 64 + mi * 16 + (l >> 4) * 4 + r;
        sred[rl][wc] = psr[mi * 4 + r];
        tred[rl][wc] = ptr_[mi * 4 + r];
      }
  }
  __syncthreads();
  if (tid < 128) {
    float sv = sred[tid][0] + sred[tid][1] + sred[tid][2] + sred[tid][3];
    float tv = tred[tid][0] + tred[tid][1] + tred[tid][2] + tred[tid][3];
    ps[h * NN + row0 + tid] = sv;
    pt[h * NN + row0 + tid] = tv;
  }
}

// ------------- K3: reduce_add — out[featH|s|t] = pA + pB (48MB streaming)
__global__ __launch_bounds__(256) void reduce_add(const float* __restrict__ pA,
                                                  const float* __restrict__ pB,
                                                  float* __restrict__ outw) {
  size_t base = ((size_t)blockIdx.x * 256 + threadIdx.x) * 16;
#pragma unroll
  for (int q = 0; q < 4; ++q) {
    float4 a = *(const float4*)(pA + base + q * 4);
    float4 b = *(const float4*)(pB + base + q * 4);
    float4 o = make_float4(a.x + b.x, a.y + b.y, a.z + b.z, a.w + b.w);
    *(float4*)(outw + base + q * 4) = o;
  }
}

// ---------- K4: aggregate — block = (head, 8 nodes), 32-lane group/node,
// float4 gathers within the head's 2MB L2-resident slice.
__global__ __launch_bounds__(256) void aggregate(const float* __restrict__ featH,
                                                 const float* __restrict__ s_arr,
                                                 const float* __restrict__ t_arr,
                                                 const int* __restrict__ deg_arr,
                                                 const int* __restrict__ idx_arr,
                                                 const float* __restrict__ bias,
                                                 float* __restrict__ out) {
  const int b = blockIdx.x;
  const int h = b >> 9;               // h-major: all XCDs on one head at a time
  const int i = ((b & 511) << 3) + (threadIdx.x >> 5);
  const int s32 = threadIdx.x & 31;
  const int slot = threadIdx.x >> 5;
  __shared__ int jj[8][MAXDEG];
  __shared__ float p[8][MAXDEG];

  const int deg = deg_arr[i];
  const float si = s_arr[h * NN + i];
  float e[4];
#pragma unroll
  for (int c = 0; c < 4; ++c) {
    int k = s32 + c * 32;
    int j = (k < deg) ? idx_arr[i * MAXDEG + k] : 0;
    if (k < deg) jj[slot][k] = j;
    if (k < deg) {
      float x = si + t_arr[h * NN + j];
      e[c] = x > 0.0f ? x : ALPHA * x;
    } else {
      e[c] = -3e38f;
    }
  }
  float m = fmaxf(fmaxf(e[0], e[1]), fmaxf(e[2], e[3]));
#pragma unroll
  for (int mask = 1; mask <= 16; mask <<= 1) m = fmaxf(m, __shfl_xor(m, mask));
  float pv[4], sum = 0.0f;
#pragma unroll
  for (int c = 0; c < 4; ++c) {
    pv[c] = __expf(e[c] - m);  // inactive lanes: exp(-huge)=0
    sum += pv[c];
  }
#pragma unroll
  for (int mask = 1; mask <= 16; mask <<= 1) sum += __shfl_xor(sum, mask);
  const float inv = 1.0f / sum;
#pragma unroll
  for (int c = 0; c < 4; ++c) p[slot][s32 + c * 32] = pv[c];

  const float* fb = featH + (size_t)h * NN * UU + s32 * 4;
  float ax = 0.0f, ay = 0.0f, az = 0.0f, aw = 0.0f;
  int k = 0;
  for (; k + 3 < deg; k += 4) {
    int j0 = jj[slot][k], j1 = jj[slot][k + 1];
    int j2 = jj[slot][k + 2], j3 = jj[slot][k + 3];
    float p0 = p[slot][k], p1 = p[slot][k + 1];
    float p2 = p[slot][k + 2], p3 = p[slot][k + 3];
    float4 v0 = *(const float4*)(fb + (size_t)j0 * UU);
    float4 v1 = *(const float4*)(fb + (size_t)j1 * UU);
    float4 v2 = *(const float4*)(fb + (size_t)j2 * UU);
    float4 v3 = *(const float4*)(fb + (size_t)j3 * UU);
    ax += p0 * v0.x + p1 * v1.x + p2 * v2.x + p3 * v3.x;
    ay += p0 * v0.y + p1 * v1.y + p2 * v2.y + p3 * v3.y;
    az += p0 * v0.z + p1 * v1.z + p2 * v2.z + p3 * v3.z;
    aw += p0 * v0.w + p1 * v1.w + p2 * v2.w + p3 * v3.w;
  }
  for (; k < deg; ++k) {
    float pk = p[slot][k];
    float4 v = *(const float4*)(fb + (size_t)jj[slot][k] * UU);
    ax += pk * v.x; ay += pk * v.y; az += pk * v.z; aw += pk * v.w;
  }
  const float4 b4 = *(const float4*)(bias + h * UU + s32 * 4);
  float4 o;
  o.x = fmaxf(ax * inv + b4.x, 0.0f);
  o.y = fmaxf(ay * inv + b4.y, 0.0f);
  o.z = fmaxf(az * inv + b4.z, 0.0f);
  o.w = fmaxf(aw * inv + b4.w, 0.0f);
  *(float4*)(out + (size_t)i * CC + h * UU + s32 * 4) = o;
}

// ---------------------------------------------------------------- launcher
extern "C" void kernel_launch(void* const* d_in, const int* in_sizes, int n_in,
                              void* d_out, int out_size, void* d_ws, size_t ws_size,
                              hipStream_t stream) {
  const float* X       = (const float*)d_in[0];
  const float* A       = (const float*)d_in[1];
  const float* W       = (const float*)d_in[2];
  const float* a_self  = (const float*)d_in[3];
  const float* a_neigh = (const float*)d_in[4];
  const float* bias    = (const float*)d_in[5];
  float* out = (float*)d_out;

  float* featH = (float*)d_ws;            // [featH|s|t] = OUTBLK floats
  float* s_arr = featH + FEAT_ELEMS;
  float* t_arr = s_arr + ST_ELEMS;
  float* pA = featH + OUTBLK;             // partial z=0 (same layout)
  float* pB = pA + OUTBLK;                // partial z=1
  unsigned short* Xhi = (unsigned short*)(pB + OUTBLK);
  unsigned short* Xlo = Xhi + (size_t)NN * FF;
  unsigned short* WT  = Xlo + (size_t)NN * FF;  // hi+lo panels
  int* deg = (int*)(WT + (size_t)2 * HH * UU * FF);
  int* idx = deg + NN;

  hipLaunchKernelGGL(transposeW, dim3(64), dim3(256), 0, stream, W, WT);
  hipLaunchKernelGGL(prep, dim3(2048 + NN), dim3(256), 0, stream,
                     X, Xhi, Xlo, A, deg, idx);
  hipLaunchKernelGGL(gemm_mfma, dim3(512), dim3(512), 0, stream,
                     Xhi, Xlo, WT, a_self, a_neigh, pA, pB);
  hipLaunchKernelGGL(reduce_add, dim3(1040), dim3(256), 0, stream, pA, pB, featH);
  hipLaunchKernelGGL(aggregate, dim3(NN), dim3(256), 0, stream,
                     featH, s_arr, t_arr, deg, idx, bias, out);
}

// Round 14
// 200.300 us; speedup vs baseline: 1.0719x; 1.0719x over previous
//
#include <hip/hip_runtime.h>

// GraphAttention N=4096 F=1024 H=8 U=128.
// R14 == R13 resubmit (R13 never ran: container failure, infra).
// (1) split-K reverted (R12 net-negative); (2) featH stored bf16 — halves
// aggregate's L2 gather traffic (705->352MB) and gemm C-write. s/t stay fp32
// (in-register, exact). aggregate reads short4 + cvt. prep/transposeW as R11.

constexpr int NN = 4096;
constexpr int FF = 1024;
constexpr int HH = 8;
constexpr int UU = 128;
constexpr int CC = HH * UU;
constexpr int MAXDEG = 128;
constexpr float ALPHA = 0.2f;

typedef __attribute__((ext_vector_type(8))) short short8;   // 8 bf16 (4 VGPRs)
typedef __attribute__((ext_vector_type(4))) short short4v;  // 4 bf16 (8 B)
typedef __attribute__((ext_vector_type(4))) float f32x4;

__device__ inline unsigned short f2bf(float x) {  // RNE float->bf16
  unsigned u = __float_as_uint(x);
  return (unsigned short)((u + 0x7fffu + ((u >> 16) & 1u)) >> 16);
}
__device__ inline float bf2f(unsigned short h) { return __uint_as_float(((unsigned)h) << 16); }

// --------------------------- K0b: W[h][f][u] -> WT[{hi,lo}][h][u][f] (bf16)
__global__ __launch_bounds__(256) void transposeW(const float* __restrict__ W,
                                                  unsigned short* __restrict__ WT) {
  const int h = blockIdx.x >> 3, ft = blockIdx.x & 7;
  const int f0 = ft * 128;
  __shared__ unsigned short hiT[128][136];  // [u][f_local], +8 pad
  __shared__ unsigned short loT[128][136];
  const int tid = threadIdx.x;
#pragma unroll
  for (int it = 0; it < 16; ++it) {
    int idx = it * 256 + tid;  // 128 f x 32 u4
    int r = idx >> 5;
    int u4 = idx & 31;
    float4 v = *(const float4*)(W + (size_t)h * FF * UU + (size_t)(f0 + r) * UU + u4 * 4);
    float xs[4] = {v.x, v.y, v.z, v.w};
#pragma unroll
    for (int e = 0; e < 4; ++e) {
      unsigned short hb = f2bf(xs[e]);
      hiT[u4 * 4 + e][r] = hb;
      loT[u4 * 4 + e][r] = f2bf(xs[e] - bf2f(hb));
    }
  }
  __syncthreads();
#pragma unroll
  for (int it = 0; it < 8; ++it) {
    int idx = it * 256 + tid;  // 128 u x 16 f8
    int u = idx >> 4, f8 = idx & 15;
    short8 vh = *(const short8*)&hiT[u][f8 * 8];
    short8 vl = *(const short8*)&loT[u][f8 * 8];
    size_t o = (size_t)h * UU * FF + (size_t)u * FF + f0 + f8 * 8;
    *(short8*)(WT + o) = vh;
    *(short8*)(WT + (size_t)HH * UU * FF + o) = vl;
  }
}

// ---------------- K1: fused prep — convert_X (blocks 0..2047) ∥ build_csr
__global__ __launch_bounds__(256) void prep(const float* __restrict__ X,
                                            unsigned short* __restrict__ Xhi,
                                            unsigned short* __restrict__ Xlo,
                                            const float* __restrict__ A,
                                            int* __restrict__ deg,
                                            int* __restrict__ idx) {
  const int tid = threadIdx.x;
  if (blockIdx.x < 2048) {  // ---- convert_X part
    size_t base = ((size_t)blockIdx.x * 256 + tid) * 8;
    float4 v0 = *(const float4*)(X + base);
    float4 v1 = *(const float4*)(X + base + 4);
    float xs[8] = {v0.x, v0.y, v0.z, v0.w, v1.x, v1.y, v1.z, v1.w};
    short8 vh, vl;
#pragma unroll
    for (int e = 0; e < 8; ++e) {
      unsigned short hb = f2bf(xs[e]);
      vh[e] = (short)hb;
      vl[e] = (short)f2bf(xs[e] - bf2f(hb));
    }
    *(short8*)(Xhi + base) = vh;
    *(short8*)(Xlo + base) = vl;
    return;
  }
  // ---- build_csr part (ballot compaction)
  const int i = blockIdx.x - 2048;
  const int lane = tid & 63;
  __shared__ int cnt;
  if (tid == 0) cnt = 0;
  __syncthreads();
  const float4* row = reinterpret_cast<const float4*>(A + (size_t)i * NN);
  for (int c = tid; c < NN / 4; c += 256) {
    float4 v = row[c];
    unsigned long long m0 = __ballot(v.x > 0.5f);
    unsigned long long m1 = __ballot(v.y > 0.5f);
    unsigned long long m2 = __ballot(v.z > 0.5f);
    unsigned long long m3 = __ballot(v.w > 0.5f);
    int wtot = __popcll(m0) + __popcll(m1) + __popcll(m2) + __popcll(m3);
    if (wtot) {
      int base = 0;
      if (lane == 0) base = atomicAdd(&cnt, wtot);
      base = __shfl(base, 0);
      unsigned long long lt = (1ull << lane) - 1;
      int c0 = __popcll(m0), c1 = __popcll(m1), c2 = __popcll(m2);
      int o;
      o = base + __popcll(m0 & lt);
      if (v.x > 0.5f && o < MAXDEG) idx[i * MAXDEG + o] = c * 4 + 0;
      o = base + c0 + __popcll(m1 & lt);
      if (v.y > 0.5f && o < MAXDEG) idx[i * MAXDEG + o] = c * 4 + 1;
      o = base + c0 + c1 + __popcll(m2 & lt);
      if (v.z > 0.5f && o < MAXDEG) idx[i * MAXDEG + o] = c * 4 + 2;
      o = base + c0 + c1 + c2 + __popcll(m3 & lt);
      if (v.w > 0.5f && o < MAXDEG) idx[i * MAXDEG + o] = c * 4 + 3;
    }
  }
  __syncthreads();
  if (tid == 0) deg[i] = cnt > MAXDEG ? MAXDEG : cnt;
}

// --------------------- K2: feat = X @ W via split-bf16 MFMA (K=3*1024)
// Single-pass (R11 structure). C written head-major bf16: featHb[h][n][u].
constexpr int NTILE = 48;  // 3 segments * 16 K-tiles of 64

__global__ __launch_bounds__(512) void gemm_mfma(const unsigned short* __restrict__ Xhi,
                                                 const unsigned short* __restrict__ Xlo,
                                                 const unsigned short* __restrict__ WT,
                                                 const float* __restrict__ a_self,
                                                 const float* __restrict__ a_neigh,
                                                 unsigned short* __restrict__ featHb,
                                                 float* __restrict__ s_arr,
                                                 float* __restrict__ t_arr) {
  __shared__ char lds[2][32768];  // [buf][ A 16K | B 16K ]
  const int tid = threadIdx.x;
  const int w = tid >> 6, l = tid & 63;
  const int h = blockIdx.x >> 5;             // head = high bits
  const int row0 = (blockIdx.x & 31) * 128;  // rowtile = low bits -> XCD=rt%8
  const int wr = w >> 2, wc = w & 3;

  const int lr = l >> 3;                 // staged LDS row within 8-row group
  const int sk = ((l & 7) ^ lr) * 8;     // inverse-swizzled source k-elem
  const unsigned short* WTh = WT + (size_t)h * UU * FF;

  f32x4 acc[4][2] = {};

  auto stage = [&](int t, int buf) {
    int s = t >> 4, kt = t & 15;
    const unsigned short* As = ((s == 1) ? Xlo : Xhi) +
        (size_t)(row0 + w * 16 + lr) * FF + kt * 64 + sk;
    const unsigned short* Bs = WTh + ((s == 2) ? (size_t)HH * UU * FF : (size_t)0) +
        (size_t)(w * 16 + lr) * FF + kt * 64 + sk;
    char* la = &lds[buf][w * 2048];
    char* lb = &lds[buf][16384 + w * 2048];
#pragma unroll
    for (int dr = 0; dr < 2; ++dr) {
      __builtin_amdgcn_global_load_lds(
          (const __attribute__((address_space(1))) unsigned int*)(As + (size_t)dr * 8 * FF),
          (__attribute__((address_space(3))) unsigned int*)(la + dr * 1024), 16, 0, 0);
      __builtin_amdgcn_global_load_lds(
          (const __attribute__((address_space(1))) unsigned int*)(Bs + (size_t)dr * 8 * FF),
          (__attribute__((address_space(3))) unsigned int*)(lb + dr * 1024), 16, 0, 0);
    }
  };

  const int arow = wr * 64 + (l & 15);
  const int bcol = wc * 32 + (l & 15);
  const int kswz = (l & 7) << 4;
  const int kb = (l >> 4) * 16;

  auto compute = [&](int buf) {
#pragma unroll
    for (int ks = 0; ks < 2; ++ks) {
      const int ko = ks * 64 + kb;
      short8 a[4], b[2];
#pragma unroll
      for (int mi = 0; mi < 4; ++mi)
        a[mi] = *(const short8*)(&lds[buf][(arow + mi * 16) * 128 + (ko ^ kswz)]);
#pragma unroll
      for (int ni = 0; ni < 2; ++ni)
        b[ni] = *(const short8*)(&lds[buf][16384 + (bcol + ni * 16) * 128 + (ko ^ kswz)]);
#pragma unroll
      for (int mi = 0; mi < 4; ++mi)
#pragma unroll
        for (int ni = 0; ni < 2; ++ni)
          acc[mi][ni] = __builtin_amdgcn_mfma_f32_16x16x32_bf16(a[mi], b[ni],
                                                                acc[mi][ni], 0, 0, 0);
    }
  };

  stage(0, 0);
  __syncthreads();
  for (int tt = 0; tt < NTILE; ++tt) {
    if (tt + 1 < NTILE) stage(tt + 1, (tt + 1) & 1);
    compute(tt & 1);
    __syncthreads();
  }

  // ---- C write (head-major, bf16): featHb[h][row][u]
  unsigned short* fh = featHb + (size_t)h * NN * UU;
  const int cu = wc * 32 + (l & 15);
  const int crow0 = row0 + wr * 64 + (l >> 4) * 4;
#pragma unroll
  for (int mi = 0; mi < 4; ++mi)
#pragma unroll
    for (int ni = 0; ni < 2; ++ni)
#pragma unroll
      for (int r = 0; r < 4; ++r)
        fh[(size_t)(crow0 + mi * 16 + r) * UU + cu + ni * 16] = f2bf(acc[mi][ni][r]);

  // ---- fused s/t (fp32, exact): s[n] = feat_row . a_self, t = . a_neigh
  const float as0 = a_self[h * UU + cu], as1 = a_self[h * UU + cu + 16];
  const float an0 = a_neigh[h * UU + cu], an1 = a_neigh[h * UU + cu + 16];
  float ps[16], pt[16];
#pragma unroll
  for (int mi = 0; mi < 4; ++mi)
#pragma unroll
    for (int r = 0; r < 4; ++r) {
      ps[mi * 4 + r] = acc[mi][0][r] * as0 + acc[mi][1][r] * as1;
      pt[mi * 4 + r] = acc[mi][0][r] * an0 + acc[mi][1][r] * an1;
    }
#pragma unroll
  for (int mask = 1; mask <= 8; mask <<= 1)
#pragma unroll
    for (int q = 0; q < 16; ++q) {
      ps[q] += __shfl_xor(ps[q], mask);
      pt[q] += __shfl_xor(pt[q], mask);
    }
  float(*sred)[4] = (float(*)[4]) & lds[0][0];      // [128][4]
  float(*tred)[4] = (float(*)[4]) & lds[0][2048];   // [128][4]
  if ((l & 15) == 0) {
#pragma unroll
    for (int mi = 0; mi < 4; ++mi)
#pragma unroll
      for (int r = 0; r < 4; ++r) {
        int rl = wr * 64 + mi * 16 + (l >> 4) * 4 + r;
        sred[rl][wc] = ps[mi * 4 + r];
        tred[rl][wc] = pt[mi * 4 + r];
      }
  }
  __syncthreads();
  if (tid < 128) {
    float sv = sred[tid][0] + sred[tid][1] + sred[tid][2] + sred[tid][3];
    float tv = tred[tid][0] + tred[tid][1] + tred[tid][2] + tred[tid][3];
    s_arr[h * NN + row0 + tid] = sv;
    t_arr[h * NN + row0 + tid] = tv;
  }
}

// ---------- K4: aggregate — block = (head, 8 nodes), 32-lane group/node,
// bf16 short4 gathers within the head's 1MB L2-resident slice.
__global__ __launch_bounds__(256) void aggregate(const unsigned short* __restrict__ featHb,
                                                 const float* __restrict__ s_arr,
                                                 const float* __restrict__ t_arr,
                                                 const int* __restrict__ deg_arr,
                                                 const int* __restrict__ idx_arr,
                                                 const float* __restrict__ bias,
                                                 float* __restrict__ out) {
  const int b = blockIdx.x;
  const int h = b >> 9;               // h-major: all XCDs on one head at a time
  const int i = ((b & 511) << 3) + (threadIdx.x >> 5);
  const int s32 = threadIdx.x & 31;
  const int slot = threadIdx.x >> 5;
  __shared__ int jj[8][MAXDEG];
  __shared__ float p[8][MAXDEG];

  const int deg = deg_arr[i];
  const float si = s_arr[h * NN + i];
  float e[4];
#pragma unroll
  for (int c = 0; c < 4; ++c) {
    int k = s32 + c * 32;
    int j = (k < deg) ? idx_arr[i * MAXDEG + k] : 0;
    if (k < deg) jj[slot][k] = j;
    if (k < deg) {
      float x = si + t_arr[h * NN + j];
      e[c] = x > 0.0f ? x : ALPHA * x;
    } else {
      e[c] = -3e38f;
    }
  }
  float m = fmaxf(fmaxf(e[0], e[1]), fmaxf(e[2], e[3]));
#pragma unroll
  for (int mask = 1; mask <= 16; mask <<= 1) m = fmaxf(m, __shfl_xor(m, mask));
  float pv[4], sum = 0.0f;
#pragma unroll
  for (int c = 0; c < 4; ++c) {
    pv[c] = __expf(e[c] - m);  // inactive lanes: exp(-huge)=0
    sum += pv[c];
  }
#pragma unroll
  for (int mask = 1; mask <= 16; mask <<= 1) sum += __shfl_xor(sum, mask);
  const float inv = 1.0f / sum;
#pragma unroll
  for (int c = 0; c < 4; ++c) p[slot][s32 + c * 32] = pv[c];

  // gather: lane owns channels s32*4..+3 (bf16, 8B/lane, 256B/row coalesced)
  const unsigned short* fb = featHb + (size_t)h * NN * UU + s32 * 4;
  float ax = 0.0f, ay = 0.0f, az = 0.0f, aw = 0.0f;
  int k = 0;
  for (; k + 3 < deg; k += 4) {
    int j0 = jj[slot][k], j1 = jj[slot][k + 1];
    int j2 = jj[slot][k + 2], j3 = jj[slot][k + 3];
    float p0 = p[slot][k], p1 = p[slot][k + 1];
    float p2 = p[slot][k + 2], p3 = p[slot][k + 3];
    short4v v0 = *(const short4v*)(fb + (size_t)j0 * UU);
    short4v v1 = *(const short4v*)(fb + (size_t)j1 * UU);
    short4v v2 = *(const short4v*)(fb + (size_t)j2 * UU);
    short4v v3 = *(const short4v*)(fb + (size_t)j3 * UU);
    ax += p0 * bf2f(v0[0]) + p1 * bf2f(v1[0]) + p2 * bf2f(v2[0]) + p3 * bf2f(v3[0]);
    ay += p0 * bf2f(v0[1]) + p1 * bf2f(v1[1]) + p2 * bf2f(v2[1]) + p3 * bf2f(v3[1]);
    az += p0 * bf2f(v0[2]) + p1 * bf2f(v1[2]) + p2 * bf2f(v2[2]) + p3 * bf2f(v3[2]);
    aw += p0 * bf2f(v0[3]) + p1 * bf2f(v1[3]) + p2 * bf2f(v2[3]) + p3 * bf2f(v3[3]);
  }
  for (; k < deg; ++k) {
    float pk = p[slot][k];
    short4v v = *(const short4v*)(fb + (size_t)jj[slot][k] * UU);
    ax += pk * bf2f(v[0]); ay += pk * bf2f(v[1]);
    az += pk * bf2f(v[2]); aw += pk * bf2f(v[3]);
  }
  const float4 b4 = *(const float4*)(bias + h * UU + s32 * 4);
  float4 o;
  o.x = fmaxf(ax * inv + b4.x, 0.0f);
  o.y = fmaxf(ay * inv + b4.y, 0.0f);
  o.z = fmaxf(az * inv + b4.z, 0.0f);
  o.w = fmaxf(aw * inv + b4.w, 0.0f);
  *(float4*)(out + (size_t)i * CC + h * UU + s32 * 4) = o;
}

// ---------------------------------------------------------------- launcher
extern "C" void kernel_launch(void* const* d_in, const int* in_sizes, int n_in,
                              void* d_out, int out_size, void* d_ws, size_t ws_size,
                              hipStream_t stream) {
  const float* X       = (const float*)d_in[0];
  const float* A       = (const float*)d_in[1];
  const float* W       = (const float*)d_in[2];
  const float* a_self  = (const float*)d_in[3];
  const float* a_neigh = (const float*)d_in[4];
  const float* bias    = (const float*)d_in[5];
  float* out = (float*)d_out;

  unsigned short* featHb = (unsigned short*)d_ws;          // 8 MB [H][N][U] bf16
  unsigned short* Xhi = featHb + (size_t)NN * CC;          // 8 MB
  unsigned short* Xlo = Xhi + (size_t)NN * FF;             // 8 MB
  unsigned short* WT  = Xlo + (size_t)NN * FF;             // 4 MB (hi+lo)
  float* s_arr = (float*)(WT + (size_t)2 * HH * UU * FF);
  float* t_arr = s_arr + HH * NN;
  int* deg = (int*)(t_arr + HH * NN);
  int* idx = deg + NN;

  hipLaunchKernelGGL(transposeW, dim3(64), dim3(256), 0, stream, W, WT);
  hipLaunchKernelGGL(prep, dim3(2048 + NN), dim3(256), 0, stream,
                     X, Xhi, Xlo, A, deg, idx);
  hipLaunchKernelGGL(gemm_mfma, dim3(256), dim3(512), 0, stream,
                     Xhi, Xlo, WT, a_self, a_neigh, featHb, s_arr, t_arr);
  hipLaunchKernelGGL(aggregate, dim3(NN), dim3(256), 0, stream,
                     featHb, s_arr, t_arr, deg, idx, bias, out);
}